// Round 1
// 256.239 us; speedup vs baseline: 1.0656x; 1.0656x over previous
//
#include <hip/hip_runtime.h>
#include <hip/hip_bf16.h>

#define LOG2E 1.4426950408889634f

typedef __attribute__((ext_vector_type(8))) short frag_ab;   // 8 bf16 (4 VGPRs)
typedef __attribute__((ext_vector_type(4))) float frag_cd;   // 4 fp32 acc

// fp32 -> bf16 bits, round-to-nearest-even (inputs finite)
__device__ inline short f2bf(float f) {
    union { float f; unsigned u; } v; v.f = f;
    unsigned r = v.u + 0x7fffu + ((v.u >> 16) & 1u);
    return (short)(r >> 16);
}

// x += row_ror<N>(x) on the VALU pipe (DPP), within each 16-lane row.
// Chain of ror 1,2,4,8 -> every lane holds the full 16-lane row sum.
template<int CTRL>
__device__ inline float dpp_ror_add(float x) {
    int t = __builtin_amdgcn_update_dpp(0, __builtin_bit_cast(int, x), CTRL, 0xf, 0xf, false);
    return x + __builtin_bit_cast(float, t);
}

// Blocks 0..63: convert W[128][1024] fp32 -> wbf bf16 in MFMA *fragment order*:
//   element (h,k): chunk c=k>>6, kstep s=(k>>5)&1, kg=(k>>3)&3, j=k&7,
//   ntile nt=h>>4, m=h&15, lane=kg*16+m
//   wbf[ (((c*8+nt)*2+s)*64 + lane)*8 + j ]
// Blocks 64..191: rmm[h] = log2e*max_k cov[h,:], rmm[128+h] = log2e*min_k.
__global__ __launch_bounds__(256) void prep_kernel(const float* __restrict__ W,
                                                   const float* __restrict__ cov,
                                                   short* __restrict__ wbf,
                                                   float* __restrict__ rmm) {
    if (blockIdx.x < 64) {
        int g = blockIdx.x * 256 + threadIdx.x;   // 0..16383
        int h = g >> 7;
        int k0 = (g & 127) << 3;
        const float* src = W + h * 1024 + k0;
        float4 w0 = *(const float4*)src;
        float4 w1 = *(const float4*)(src + 4);
        frag_ab af;
        af[0] = f2bf(w0.x); af[1] = f2bf(w0.y); af[2] = f2bf(w0.z); af[3] = f2bf(w0.w);
        af[4] = f2bf(w1.x); af[5] = f2bf(w1.y); af[6] = f2bf(w1.z); af[7] = f2bf(w1.w);
        int c = k0 >> 6, s = (k0 >> 5) & 1, kg = (k0 >> 3) & 3;
        int nt = h >> 4, m = h & 15, lane = kg * 16 + m;
        int dst = (((c * 8 + nt) * 2 + s) * 64 + lane) * 8;
        *(frag_ab*)(wbf + dst) = af;
    } else {
        int h = blockIdx.x - 64;
        int lane = threadIdx.x;
        if (lane < 64) {
            float c1 = cov[h * 128 + lane];
            float c2 = cov[h * 128 + 64 + lane];
            float mx = fmaxf(c1, c2), mn = fminf(c1, c2);
            for (int o = 1; o < 64; o <<= 1) {
                mx = fmaxf(mx, __shfl_xor(mx, o, 64));
                mn = fminf(mn, __shfl_xor(mn, o, 64));
            }
            if (lane == 0) { rmm[h] = LOG2E * mx; rmm[128 + h] = LOG2E * mn; }
        }
    }
}

// Fused: phase 1 = proj (64 rows x 128 h, bf16 MFMA, B staged in LDS double-buffer,
// A prefetched from global). Accumulator goes to LDS (aliasing the dead B buffers),
// never to HBM. Phase 2 = softmax-combine for the block's 32 b's:
//   thread (i=t>>4, j=t&15) owns h in [8i,8i+8), k in [8j,8j+8).
//   lsum over 128 k: 8 local adds + 4 DPP row_ror adds (VALU pipe, zero DS ops).
//   h-reduction: all 256 threads write partials to obuf, 2 b's per barrier pair,
//   256-thread final sum (no idle-lane tail).
__global__ __launch_bounds__(256, 2) void fused_kernel(const float* __restrict__ x,
                                                       const short* __restrict__ wbf,
                                                       const float* __restrict__ cov,
                                                       const float* __restrict__ bias,
                                                       const float* __restrict__ rmm,
                                                       float* __restrict__ out) {
    // phase 1: Bs[2][8192] shorts (2 x 16 KB) ; phase 2: vmf[64][132] floats (33792 B)
    __shared__ __align__(16) char smem[64 * 132 * 4];
    __shared__ float obuf[2][16][132];
    __shared__ float bias_s[128];

    const int tid = threadIdx.x;
    const int lane = tid & 63, wave = tid >> 6;
    const int m = lane & 15, kg = lane >> 4;
    const long rowbase = (long)blockIdx.x * 64 + wave * 16;
    const float* xrow = x + (rowbase + m) * 1024 + kg * 8;

    if (tid < 128) bias_s[tid] = bias[tid];

    frag_cd acc[8];
#pragma unroll
    for (int nt = 0; nt < 8; ++nt) acc[nt] = (frag_cd){0.f, 0.f, 0.f, 0.f};

    // stage B chunk 0
    {
        const char* wc = (const char*)wbf;
        float4 t0 = *(const float4*)(wc + tid * 16);
        float4 t1 = *(const float4*)(wc + 4096 + tid * 16);
        float4 t2 = *(const float4*)(wc + 8192 + tid * 16);
        float4 t3 = *(const float4*)(wc + 12288 + tid * 16);
        char* bd = smem + tid * 16;
        *(float4*)(bd)         = t0;
        *(float4*)(bd + 4096)  = t1;
        *(float4*)(bd + 8192)  = t2;
        *(float4*)(bd + 12288) = t3;
    }
    // prefetch A chunk 0
    float4 a0 = *(const float4*)(xrow);
    float4 a1 = *(const float4*)(xrow + 4);
    float4 a2 = *(const float4*)(xrow + 32);
    float4 a3 = *(const float4*)(xrow + 36);
    __syncthreads();

    int cb = 0;
    for (int c = 0; c < 16; ++c) {
        float4 n0, n1, n2, n3, B0, B1, B2, B3;
        if (c < 15) {
            const float* xn = xrow + (c + 1) * 64;
            n0 = *(const float4*)(xn);
            n1 = *(const float4*)(xn + 4);
            n2 = *(const float4*)(xn + 32);
            n3 = *(const float4*)(xn + 36);
            const char* wc = (const char*)wbf + (c + 1) * 16384;
            B0 = *(const float4*)(wc + tid * 16);
            B1 = *(const float4*)(wc + 4096 + tid * 16);
            B2 = *(const float4*)(wc + 8192 + tid * 16);
            B3 = *(const float4*)(wc + 12288 + tid * 16);
        }
        frag_ab af0, af1;
        af0[0] = f2bf(a0.x); af0[1] = f2bf(a0.y); af0[2] = f2bf(a0.z); af0[3] = f2bf(a0.w);
        af0[4] = f2bf(a1.x); af0[5] = f2bf(a1.y); af0[6] = f2bf(a1.z); af0[7] = f2bf(a1.w);
        af1[0] = f2bf(a2.x); af1[1] = f2bf(a2.y); af1[2] = f2bf(a2.z); af1[3] = f2bf(a2.w);
        af1[4] = f2bf(a3.x); af1[5] = f2bf(a3.y); af1[6] = f2bf(a3.z); af1[7] = f2bf(a3.w);

        const char* bs = smem + cb * 16384;
#pragma unroll
        for (int nt = 0; nt < 8; ++nt) {
            frag_ab bf0 = *(const frag_ab*)(bs + (nt * 2 + 0) * 1024 + lane * 16);
            acc[nt] = __builtin_amdgcn_mfma_f32_16x16x32_bf16(af0, bf0, acc[nt], 0, 0, 0);
            frag_ab bf1 = *(const frag_ab*)(bs + (nt * 2 + 1) * 1024 + lane * 16);
            acc[nt] = __builtin_amdgcn_mfma_f32_16x16x32_bf16(af1, bf1, acc[nt], 0, 0, 0);
        }
        if (c < 15) {
            char* bd = smem + (cb ^ 1) * 16384 + tid * 16;
            *(float4*)(bd)         = B0;
            *(float4*)(bd + 4096)  = B1;
            *(float4*)(bd + 8192)  = B2;
            *(float4*)(bd + 12288) = B3;
            a0 = n0; a1 = n1; a2 = n2; a3 = n3;
        }
        __syncthreads();
        cb ^= 1;
    }
    // K-loop ended with __syncthreads(): all Bs reads drained -> safe to alias.

    // ---- phase 2 setup: per-thread cov fragment (log2e-scaled) + rmm extrema ----
    const int i = tid >> 4;   // h-group: h in [8i, 8i+8)
    const int j = tid & 15;   // k-group: k in [8j, 8j+8)
    float covreg[8][8];
#pragma unroll
    for (int hh = 0; hh < 8; ++hh) {
        const float* cr = cov + (long)(i * 8 + hh) * 128 + j * 8;
        float4 c0 = *(const float4*)cr;
        float4 c1 = *(const float4*)(cr + 4);
        covreg[hh][0] = LOG2E * c0.x; covreg[hh][1] = LOG2E * c0.y;
        covreg[hh][2] = LOG2E * c0.z; covreg[hh][3] = LOG2E * c0.w;
        covreg[hh][4] = LOG2E * c1.x; covreg[hh][5] = LOG2E * c1.y;
        covreg[hh][6] = LOG2E * c1.z; covreg[hh][7] = LOG2E * c1.w;
    }
    float rmx[8], rmn[8];
#pragma unroll
    for (int hh = 0; hh < 8; ++hh) {
        rmx[hh] = rmm[i * 8 + hh];
        rmn[hh] = rmm[128 + i * 8 + hh];
    }

    // store accumulator to LDS (stride 132 -> 2-way bank aliasing only, free)
    float* vmf = (float*)smem;
#pragma unroll
    for (int nt = 0; nt < 8; ++nt)
#pragma unroll
        for (int r = 0; r < 4; ++r)
            vmf[(wave * 16 + kg * 4 + r) * 132 + nt * 16 + m] = acc[nt][r];
    __syncthreads();

    const long outbase = (long)blockIdx.x * 32 * 128;
    for (int bl2 = 0; bl2 < 16; ++bl2) {
#pragma unroll
        for (int sb = 0; sb < 2; ++sb) {
            const int bl = bl2 * 2 + sb;
            const float* vrow = vmf + (2 * bl) * 132 + i * 8;
            const float* mrow = vmf + (2 * bl + 1) * 132 + i * 8;
            float4 v0  = *(const float4*)(vrow);
            float4 v1  = *(const float4*)(vrow + 4);
            float4 mk0 = *(const float4*)(mrow);
            float4 mk1 = *(const float4*)(mrow + 4);
            float vh[8] = {v0.x, v0.y, v0.z, v0.w, v1.x, v1.y, v1.z, v1.w};
            float mh[8] = {mk0.x, mk0.y, mk0.z, mk0.w, mk1.x, mk1.y, mk1.z, mk1.w};
            float op[8] = {0.f, 0.f, 0.f, 0.f, 0.f, 0.f, 0.f, 0.f};
#pragma unroll
            for (int hh = 0; hh < 8; ++hh) {
                float mv = mh[hh];
                float mmax = mv * (mv >= 0.f ? rmx[hh] : rmn[hh]);
                float p[8];
                float lsum = 0.f;
#pragma unroll
                for (int kk = 0; kk < 8; ++kk) {
                    float e = __builtin_amdgcn_exp2f(fmaf(mv, covreg[hh][kk], -mmax));
                    p[kk] = e;
                    lsum += e;
                }
                // full 16-lane row sum on the VALU pipe (no DS traffic)
                lsum = dpp_ror_add<0x121>(lsum);   // row_ror:1
                lsum = dpp_ror_add<0x122>(lsum);   // row_ror:2
                lsum = dpp_ror_add<0x124>(lsum);   // row_ror:4
                lsum = dpp_ror_add<0x128>(lsum);   // row_ror:8
                float w = vh[hh] * __builtin_amdgcn_rcpf(lsum);
#pragma unroll
                for (int kk = 0; kk < 8; ++kk) op[kk] = fmaf(w, p[kk], op[kk]);
            }
            *(float4*)&obuf[sb][i][j * 8]     = make_float4(op[0], op[1], op[2], op[3]);
            *(float4*)&obuf[sb][i][j * 8 + 4] = make_float4(op[4], op[5], op[6], op[7]);
        }
        __syncthreads();
        // all 256 threads reduce: thread t -> sub-b = t>>7, k = t&127
        {
            const int sb = tid >> 7;
            const int k  = tid & 127;
            float o = bias_s[k];
#pragma unroll
            for (int ii = 0; ii < 16; ++ii) o += obuf[sb][ii][k];
            out[outbase + (bl2 * 2 + sb) * 128 + k] = o;
        }
        __syncthreads();
    }
}

extern "C" void kernel_launch(void* const* d_in, const int* in_sizes, int n_in,
                              void* d_out, int out_size, void* d_ws, size_t ws_size,
                              hipStream_t stream) {
    const float* x    = (const float*)d_in[0];
    const float* W    = (const float*)d_in[1];
    const float* cov  = (const float*)d_in[2];
    const float* bias = (const float*)d_in[3];
    float* out = (float*)d_out;

    const int B = in_sizes[0] / (2 * 1024);   // 16384

    short* wbf = (short*)d_ws;                // [128*1024] bf16, fragment order
    float* rmm = (float*)(wbf + 128 * 1024);  // [256]

    prep_kernel<<<192, 256, 0, stream>>>(W, cov, wbf, rmm);
    fused_kernel<<<(2 * B) / 64, 256, 0, stream>>>(x, wbf, cov, bias, rmm, out);
}